// Round 4
// baseline (1553.336 us; speedup 1.0000x reference)
//
#include <hip/hip_runtime.h>

typedef __bf16 v8bf __attribute__((ext_vector_type(8)));
typedef float  v16f __attribute__((ext_vector_type(16)));
typedef float  f4   __attribute__((ext_vector_type(4)));
typedef unsigned int uint;
typedef unsigned short ushort;
typedef uint   v4u  __attribute__((ext_vector_type(4)));
typedef uint   v2u  __attribute__((ext_vector_type(2)));

#define GLAS(p) ((const __attribute__((address_space(1))) void*)(p))
#define LDAS(p) ((__attribute__((address_space(3))) void*)(p))

__device__ __forceinline__ ushort f32_to_bf16(float f) {
    uint u = __builtin_bit_cast(uint, f);
    uint r = u + 0x7FFFu + ((u >> 16) & 1u);   // RNE; inputs finite
    return (ushort)(r >> 16);
}

// ---------------- fused BN1 column stats (partials, no atomics) + fp32->bf16 ----------------
// Thread handles 4 adjacent columns; reads float4, writes 4xbf16 (8B).
// Partial sums per blockIdx.y written to ps/pq [gridY][ncols].
__global__ __launch_bounds__(256) void colstats_cvt(
    const float* __restrict__ x, ushort* __restrict__ xb,
    float* __restrict__ ps, float* __restrict__ pq, int ncols, int rows) {
    int c4 = blockIdx.x * blockDim.x + threadIdx.x;   // column quad index
    int q = ncols >> 2;
    size_t base = (size_t)blockIdx.y * rows * q + c4;
    const f4* x4 = (const f4*)x;
    v2u* o = (v2u*)xb;
    f4 s = {0.f, 0.f, 0.f, 0.f}, qq = {0.f, 0.f, 0.f, 0.f};
#pragma unroll 4
    for (int r = 0; r < rows; ++r) {
        f4 v = x4[base + (size_t)r * q];
        s += v; qq += v * v;
        union { ushort us[4]; v2u u; } p;
        p.us[0] = f32_to_bf16(v.x); p.us[1] = f32_to_bf16(v.y);
        p.us[2] = f32_to_bf16(v.z); p.us[3] = f32_to_bf16(v.w);
        o[base + (size_t)r * q] = p.u;
    }
    ((f4*)ps)[(size_t)blockIdx.y * q + c4] = s;
    ((f4*)pq)[(size_t)blockIdx.y * q + c4] = qq;
}

// finalize from partials: s,t such that BN(x) = x*s + t
__global__ void bn_finalize_part(const float* __restrict__ ps, const float* __restrict__ pq,
                                 const float* __restrict__ g, const float* __restrict__ b,
                                 float* __restrict__ s, float* __restrict__ t,
                                 float invN, int ncols, int nparts) {
    int c = blockIdx.x * blockDim.x + threadIdx.x;
    float S = 0.f, Q = 0.f;
    for (int p = 0; p < nparts; ++p) {
        S += ps[(size_t)p * ncols + c];
        Q += pq[(size_t)p * ncols + c];
    }
    float m = S * invN;
    float var = fmaxf(Q * invN - m * m, 0.f);
    float rs = rsqrtf(var + 1e-5f);
    float sc = rs * g[c];
    s[c] = sc;
    t[c] = b[c] - m * sc;
}

// finalize from atomic sums (layer 2)
__global__ void bn_finalize(const float* __restrict__ sum, const float* __restrict__ ssum,
                            const float* __restrict__ g, const float* __restrict__ b,
                            float* __restrict__ s, float* __restrict__ t, float invN) {
    int c = blockIdx.x * blockDim.x + threadIdx.x;
    float m = sum[c] * invN;
    float var = fmaxf(ssum[c] * invN - m * m, 0.f);
    float rs = rsqrtf(var + 1e-5f);
    float sc = rs * g[c];
    s[c] = sc;
    t[c] = b[c] - m * sc;
}

// ---------------- fold BN scale/shift into weights (wave per row) ----------------
// Wp[j,k] = bf16(W[j,k]*s[k]);  bp[j] = bias[j] + sum_k W[j,k]*t[k]
__global__ __launch_bounds__(256) void fold_w(
    const float* __restrict__ W, const float* __restrict__ bias,
    const float* __restrict__ s, const float* __restrict__ t,
    ushort* __restrict__ Wp, float* __restrict__ bp, int K) {
    int row = blockIdx.x * 4 + (threadIdx.x >> 6);
    int lane = threadIdx.x & 63;
    const f4* wr = (const f4*)(W + (size_t)row * K);
    const f4* s4 = (const f4*)s;
    const f4* t4 = (const f4*)t;
    v2u* orow = (v2u*)(Wp + (size_t)row * K);
    float part = 0.f;
    int K4 = K >> 2;
    for (int k = lane; k < K4; k += 64) {
        f4 v = wr[k], sv = s4[k], tv = t4[k];
        part += v.x * tv.x + v.y * tv.y + v.z * tv.z + v.w * tv.w;
        union { ushort us[4]; v2u u; } o;
        o.us[0] = f32_to_bf16(v.x * sv.x);
        o.us[1] = f32_to_bf16(v.y * sv.y);
        o.us[2] = f32_to_bf16(v.z * sv.z);
        o.us[3] = f32_to_bf16(v.w * sv.w);
        orow[k] = o.u;
    }
#pragma unroll
    for (int off = 32; off > 0; off >>= 1) part += __shfl_down(part, off);
    if (lane == 0) bp[row] = bias[row] + part;
}

// ---------------- bf16 MFMA GEMM, B^T layout, XOR-swizzled LDS ----------------
// C[m,n] = sum_k A[m,k]*B[n,k] (+ epilogue).  128x128 tile, BK=64, 4 waves,
// each wave 64x64 via 2x2 grid of 32x32x16 MFMA.  global_load_lds width-16.
// LDS granule (row,c) at physical granule row*8 + (c ^ (row&7)) (conflict-free).
// 32x32x16 A/B frag: m(or n) = lane&31, k = (lane>>5)*8 + j.
// 32x32 C/D: col = lane&31, row = (reg&3) + 8*(reg>>2) + 4*(lane>>5)  [m74/m101]
// EPI=0: out bf16 = relu(acc + bias[col]); also accumulates per-column
//        sum/sumsq of the output into colS/colQ (BN2 stats fused).
// EPI=1: out f32  = acc + bias[col] + beta*Y[row,col]
template <int EPI>
__global__ __launch_bounds__(256) void gemm_bt(
    const ushort* __restrict__ A, const ushort* __restrict__ B,
    void* __restrict__ Cout, const float* __restrict__ bias,
    const float* __restrict__ Y, const float* __restrict__ betaPtr,
    float* __restrict__ colS, float* __restrict__ colQ,
    int M, int Ncol, int K) {
    __shared__ __align__(16) ushort lsA[128 * 64];
    __shared__ __align__(16) ushort lsB[128 * 64];
    const int tid = threadIdx.x;
    const int wave = tid >> 6, lane = tid & 63;
    const int wm = wave >> 1, wn = wave & 1;
    const int l32 = lane & 31, lq = lane >> 5;      // lq in 0..1
    const int m0 = blockIdx.y * 128, n0 = blockIdx.x * 128;

    // staging: lane l of issue (q,wave) writes physical granule
    // g = (q*4+wave)*64 + l  holding global (row = base+(l>>3), c = (l&7)^(l>>3))
    const int srow = lane >> 3;
    const int sgc  = (lane & 7) ^ (lane >> 3);

    v16f acc[2][2] = {};

    for (int k0 = 0; k0 < K; k0 += 64) {
#pragma unroll
        for (int q = 0; q < 4; ++q) {
            const int g0 = (q * 4 + wave) << 6;
            const int row = (g0 >> 3) + srow;
            const ushort* sa = A + (size_t)(m0 + row) * K + k0 + sgc * 8;
            const ushort* sb = B + (size_t)(n0 + row) * K + k0 + sgc * 8;
            __builtin_amdgcn_global_load_lds(GLAS(sa), LDAS(&lsA[g0 * 8]), 16, 0, 0);
            __builtin_amdgcn_global_load_lds(GLAS(sb), LDAS(&lsB[g0 * 8]), 16, 0, 0);
        }
        __syncthreads();
#pragma unroll
        for (int kk = 0; kk < 64; kk += 16) {
            v8bf a[2], b[2];
            const int cbase = (kk >> 3) + lq;        // logical granule col 0..7
#pragma unroll
            for (int i = 0; i < 2; ++i) {
                const int ra = wm * 64 + i * 32 + l32;
                const int pa = ra * 8 + (cbase ^ (ra & 7));
                a[i] = __builtin_bit_cast(v8bf, *(const v4u*)&lsA[pa * 8]);
            }
#pragma unroll
            for (int j = 0; j < 2; ++j) {
                const int rb = wn * 64 + j * 32 + l32;
                const int pb = rb * 8 + (cbase ^ (rb & 7));
                b[j] = __builtin_bit_cast(v8bf, *(const v4u*)&lsB[pb * 8]);
            }
#pragma unroll
            for (int i = 0; i < 2; ++i)
#pragma unroll
                for (int j = 0; j < 2; ++j)
                    acc[i][j] = __builtin_amdgcn_mfma_f32_32x32x16_bf16(a[i], b[j], acc[i][j], 0, 0, 0);
        }
        __syncthreads();
    }

    const float betaV = (EPI == 1) ? betaPtr[0] : 0.f;
    float sj[2] = {0.f, 0.f}, qj[2] = {0.f, 0.f};
#pragma unroll
    for (int j = 0; j < 2; ++j) {
        const int col = n0 + wn * 64 + j * 32 + l32;
        const float bj = bias[col];
#pragma unroll
        for (int i = 0; i < 2; ++i) {
#pragma unroll
            for (int reg = 0; reg < 16; ++reg) {
                const int row = m0 + wm * 64 + i * 32 + (reg & 3) + 8 * (reg >> 2) + 4 * lq;
                float v = acc[i][j][reg] + bj;
                if (EPI == 0) {
                    v = v > 0.f ? v : 0.f;
                    sj[j] += v; qj[j] += v * v;
                    ((ushort*)Cout)[(size_t)row * Ncol + col] = f32_to_bf16(v);
                } else {
                    v += betaV * Y[(size_t)row * Ncol + col];
                    ((float*)Cout)[(size_t)row * Ncol + col] = v;
                }
            }
        }
    }

    if (EPI == 0) {
        // reduce per-column partials across the 4 threads sharing each column.
        float* cs = (float*)lsA;          // [4][128]
        float* cq = cs + 512;             // [4][128]
        const int p = wm * 2 + lq;
#pragma unroll
        for (int j = 0; j < 2; ++j) {
            const int ci = wn * 64 + j * 32 + l32;
            cs[p * 128 + ci] = sj[j];
            cq[p * 128 + ci] = qj[j];
        }
        __syncthreads();
        if (tid < 128) {
            float S = cs[tid] + cs[128 + tid] + cs[256 + tid] + cs[384 + tid];
            float Q = cq[tid] + cq[128 + tid] + cq[256 + tid] + cq[384 + tid];
            atomicAdd(&colS[n0 + tid], S);
            atomicAdd(&colQ[n0 + tid], Q);
        }
    }
}

extern "C" void kernel_launch(void* const* d_in, const int* in_sizes, int n_in,
                              void* d_out, int out_size, void* d_ws, size_t ws_size,
                              hipStream_t stream) {
    const float* x    = (const float*)d_in[0];
    const float* y    = (const float*)d_in[1];
    const float* W1   = (const float*)d_in[2];
    const float* b1   = (const float*)d_in[3];
    const float* W2   = (const float*)d_in[4];
    const float* b2   = (const float*)d_in[5];
    const float* bn1g = (const float*)d_in[6];
    const float* bn1b = (const float*)d_in[7];
    const float* bn2g = (const float*)d_in[8];
    const float* bn2b = (const float*)d_in[9];
    const float* beta = (const float*)d_in[10];

    constexpr int Nb = 32768, F = 2048, H = 4096, C = 512;
    constexpr int NPART = 256;   // y-blocks for colstats_cvt

    char* w = (char*)d_ws;
    ushort* xb  = (ushort*)w;                                        // 128 MB
    ushort* h1  = (ushort*)(w + (size_t)Nb * F * 2);                 // 256 MB
    ushort* w1p = (ushort*)(w + (size_t)Nb * F * 2 + (size_t)Nb * H * 2);   // 16 MB
    ushort* w2p = (ushort*)((char*)w1p + (size_t)H * F * 2);         // 4 MB
    float*  fb  = (float*)((char*)w2p + (size_t)C * H * 2);
    float* b1p = fb;            // H
    float* b2p = b1p + H;       // C
    float* sum2 = b2p + C;      // H  (BN2 atomic sums)
    float* ss2  = sum2 + H;     // H
    float* s1   = ss2 + H;      // F
    float* t1   = s1 + F;       // F
    float* s2   = t1 + F;       // H
    float* t2   = s2 + H;       // H
    // BN1 partials live in the (not yet written) h1 region: 2 x 2MB
    float* ps1 = (float*)h1;                  // [NPART][F]
    float* pq1 = ps1 + (size_t)NPART * F;     // [NPART][F]

    hipMemsetAsync(sum2, 0, sizeof(float) * 2 * H, stream);

    // BN1 stats (partials) + x->bf16, fused
    colstats_cvt<<<dim3(F / 4 / 256, NPART), 256, 0, stream>>>(x, xb, ps1, pq1, F, Nb / NPART);
    bn_finalize_part<<<F / 256, 256, 0, stream>>>(ps1, pq1, bn1g, bn1b, s1, t1, 1.f / Nb, F, NPART);
    // fold BN1 into W1
    fold_w<<<H / 4, 256, 0, stream>>>(W1, b1, s1, t1, w1p, b1p, F);
    // h1 = relu(xb @ w1p^T + b1p) bf16; BN2 col sums fused into epilogue
    gemm_bt<0><<<dim3(H / 128, Nb / 128), 256, 0, stream>>>(
        xb, w1p, h1, b1p, nullptr, nullptr, sum2, ss2, Nb, H, F);
    bn_finalize<<<H / 256, 256, 0, stream>>>(sum2, ss2, bn2g, bn2b, s2, t2, 1.f / Nb);
    // fold BN2 into W2
    fold_w<<<C / 4, 256, 0, stream>>>(W2, b2, s2, t2, w2p, b2p, H);
    // out = h1 @ w2p^T + b2p + beta*y, fp32
    gemm_bt<1><<<dim3(C / 128, Nb / 128), 256, 0, stream>>>(
        h1, w2p, d_out, b2p, y, beta, nullptr, nullptr, Nb, C, H);
    (void)in_sizes; (void)n_in; (void)out_size; (void)ws_size;
}